// Round 1
// baseline (619.991 us; speedup 1.0000x reference)
//
#include <hip/hip_runtime.h>

// TATWindowAttention: B=16, n=100 windows, L=64, C=256, H=8, Dh=32
// out = concat(x [B,n,L,C], attn [B,n,H,L,L]) as fp32.
// One block per (b, w, h): 12800 blocks x 256 threads.

#define LOGIT_MAX_F 4.605170185988091f  // log(100)

__global__ __launch_bounds__(256) void tat_attn_kernel(
    const float* __restrict__ Qg, const float* __restrict__ Kg,
    const float* __restrict__ Vg, const float* __restrict__ Pg,
    const float* __restrict__ LSg,
    float* __restrict__ Xout, float* __restrict__ Aout)
{
    constexpr int L = 64, C = 256, Dh = 32, H = 8, NW = 100;
    constexpr int QK_STRIDE = 68;   // 17*4 floats -> rows stay 16B aligned, banks ~2-way
    constexpr int P_STRIDE  = 68;

    __shared__ float Qt[Dh * QK_STRIDE];   // d-major: Qt[d][q]
    __shared__ float Kt[Dh * QK_STRIDE];   // d-major: Kt[d][k]
    __shared__ float Vs[L * Dh];           // row-major: Vs[k][d]
    __shared__ float Ps[L * P_STRIDE];     // scores then probs: Ps[q][k]

    const int blk = blockIdx.x;
    const int h  = blk & 7;
    const int bw = blk >> 3;               // b*NW + w
    const int t  = threadIdx.x;

    const float* qb = Qg + (size_t)bw * L * C + h * Dh;
    const float* kb = Kg + (size_t)bw * L * C + h * Dh;
    const float* vb = Vg + (size_t)bw * L * C + h * Dh;
    const int b = bw / NW;
    const float* pb = Pg + (size_t)(b * H + h) * L * L;
    float* xb = Xout + (size_t)bw * L * C + h * Dh;
    float* ab = Aout + ((size_t)bw * H + h) * L * L;

    const float scale = __expf(fminf(LSg[h], LOGIT_MAX_F));

    // ---- Stage Q^T, K^T, V into LDS ----
    {
        const int row = t >> 3;            // 0..31
        const int d4  = (t & 7) << 2;      // 0,4,...,28
        #pragma unroll
        for (int p = 0; p < 2; ++p) {
            const int r = p * 32 + row;    // 0..63
            const float4 qv = *(const float4*)(qb + r * C + d4);
            const float4 kv = *(const float4*)(kb + r * C + d4);
            const float4 vv = *(const float4*)(vb + r * C + d4);
            Qt[(d4 + 0) * QK_STRIDE + r] = qv.x;
            Qt[(d4 + 1) * QK_STRIDE + r] = qv.y;
            Qt[(d4 + 2) * QK_STRIDE + r] = qv.z;
            Qt[(d4 + 3) * QK_STRIDE + r] = qv.w;
            Kt[(d4 + 0) * QK_STRIDE + r] = kv.x;
            Kt[(d4 + 1) * QK_STRIDE + r] = kv.y;
            Kt[(d4 + 2) * QK_STRIDE + r] = kv.z;
            Kt[(d4 + 3) * QK_STRIDE + r] = kv.w;
            *(float4*)(Vs + r * Dh + d4) = vv;
        }
    }
    __syncthreads();

    // ---- QK^T: 4x4 register tile per thread ----
    {
        const int tq = (t & 15) << 2;      // q tile base
        const int tk = (t >> 4) << 2;      // k tile base
        float acc[4][4];
        #pragma unroll
        for (int i = 0; i < 4; ++i)
            #pragma unroll
            for (int j = 0; j < 4; ++j) acc[i][j] = 0.0f;

        #pragma unroll 8
        for (int d = 0; d < Dh; ++d) {
            const float4 qv = *(const float4*)(Qt + d * QK_STRIDE + tq);
            const float4 kv = *(const float4*)(Kt + d * QK_STRIDE + tk);
            const float qa[4] = {qv.x, qv.y, qv.z, qv.w};
            const float ka[4] = {kv.x, kv.y, kv.z, kv.w};
            #pragma unroll
            for (int i = 0; i < 4; ++i)
                #pragma unroll
                for (int j = 0; j < 4; ++j)
                    acc[i][j] = fmaf(qa[i], ka[j], acc[i][j]);
        }
        #pragma unroll
        for (int i = 0; i < 4; ++i)
            *(float4*)(Ps + (tq + i) * P_STRIDE + tk) =
                make_float4(acc[i][0], acc[i][1], acc[i][2], acc[i][3]);
    }
    __syncthreads();

    // ---- Softmax: one wave per row, in-register reductions ----
    {
        const int wv   = t >> 6;           // 0..3
        const int lane = t & 63;
        #pragma unroll 4
        for (int it = 0; it < 16; ++it) {
            const int qq = wv * 16 + it;
            const float l = fmaf(Ps[qq * P_STRIDE + lane], scale,
                                 pb[qq * L + lane]);
            float m = l;
            #pragma unroll
            for (int off = 32; off > 0; off >>= 1)
                m = fmaxf(m, __shfl_xor(m, off));
            const float e = __expf(l - m);
            float s = e;
            #pragma unroll
            for (int off = 32; off > 0; off >>= 1)
                s += __shfl_xor(s, off);
            const float pv = e / s;
            ab[qq * L + lane] = pv;        // coalesced 256B per wave
            Ps[qq * P_STRIDE + lane] = pv;
        }
    }
    __syncthreads();

    // ---- PV: 2x4 register tile per thread ----
    {
        const int td = (t & 7) << 2;       // d tile base: 0..28
        const int q0 = (t >> 3) << 1;      // q pair: 0,2,...,62
        float a0[4] = {0, 0, 0, 0};
        float a1[4] = {0, 0, 0, 0};
        #pragma unroll 8
        for (int k = 0; k < L; ++k) {
            const float4 vv = *(const float4*)(Vs + k * Dh + td);
            const float p0 = Ps[q0 * P_STRIDE + k];
            const float p1 = Ps[(q0 + 1) * P_STRIDE + k];
            a0[0] = fmaf(p0, vv.x, a0[0]);
            a0[1] = fmaf(p0, vv.y, a0[1]);
            a0[2] = fmaf(p0, vv.z, a0[2]);
            a0[3] = fmaf(p0, vv.w, a0[3]);
            a1[0] = fmaf(p1, vv.x, a1[0]);
            a1[1] = fmaf(p1, vv.y, a1[1]);
            a1[2] = fmaf(p1, vv.z, a1[2]);
            a1[3] = fmaf(p1, vv.w, a1[3]);
        }
        *(float4*)(xb + q0 * C + td)       = make_float4(a0[0], a0[1], a0[2], a0[3]);
        *(float4*)(xb + (q0 + 1) * C + td) = make_float4(a1[0], a1[1], a1[2], a1[3]);
    }
}

extern "C" void kernel_launch(void* const* d_in, const int* in_sizes, int n_in,
                              void* d_out, int out_size, void* d_ws, size_t ws_size,
                              hipStream_t stream) {
    const float* q   = (const float*)d_in[0];
    const float* k   = (const float*)d_in[1];
    const float* v   = (const float*)d_in[2];
    const float* pos = (const float*)d_in[3];
    const float* ls  = (const float*)d_in[4];
    float* out = (float*)d_out;

    constexpr int B = 16, NW = 100, L = 64, C = 256, H = 8;
    float* x_out = out;
    float* a_out = out + (size_t)B * NW * L * C;   // 26,214,400

    const int blocks = B * NW * H;                 // 12800
    tat_attn_kernel<<<blocks, 256, 0, stream>>>(q, k, v, pos, ls, x_out, a_out);
}

// Round 2
// 540.163 us; speedup vs baseline: 1.1478x; 1.1478x over previous
//
#include <hip/hip_runtime.h>

// TATWindowAttention: B=16, n=100, L=64, C=256, H=8, Dh=32
// out = concat(x [B,n,L,C], attn [B,n,H,L,L]) fp32.
// One block per (bw, h): 12800 blocks x 256 threads (4 waves).
// MFMA 16x16x32 bf16; split-bf16 (hi+lo) Q,K for precision; bf16 P,V for PV.

typedef __attribute__((ext_vector_type(8))) short bf16x8;
typedef __attribute__((ext_vector_type(4))) float f32x4;

#define LOGIT_MAX_F 4.605170185988091f  // log(100)

__device__ __forceinline__ short f2bf(float f) {
    union { float f; unsigned u; } c; c.f = f;
    unsigned r = c.u + 0x7FFFu + ((c.u >> 16) & 1u);
    return (short)(r >> 16);
}
__device__ __forceinline__ float bf2f(short s) {
    union { unsigned u; float f; } c; c.u = ((unsigned)(unsigned short)s) << 16;
    return c.f;
}

// LDS layout (shorts): QHI[64*40] @0, QLO @2560, KHI @5120, KLO @7680,
// VT[32*72] @10240 (V transposed: VT[d][k]).  P[64*72] aliases @0 (after barrier).
#define QHI_OFF 0
#define QLO_OFF 2560
#define KHI_OFF 5120
#define KLO_OFF 7680
#define VT_OFF  10240
#define P_OFF   0
#define SMEM_SHORTS 12544   // 25088 B

__global__ __launch_bounds__(256, 5) void tat_attn_kernel(
    const float* __restrict__ Qg, const float* __restrict__ Kg,
    const float* __restrict__ Vg, const float* __restrict__ Pg,
    const float* __restrict__ LSg,
    float* __restrict__ Xout, float* __restrict__ Aout)
{
    constexpr int L = 64, C = 256, H = 8, NW = 100;
    __shared__ short smem[SMEM_SHORTS];

    const int blk = blockIdx.x;
    const int h  = blk & 7;
    const int bw = blk >> 3;
    const int t  = threadIdx.x;
    const int wave = t >> 6;
    const int lane = t & 63;
    const int quad = lane >> 4;
    const int l15  = lane & 15;

    const float* qb = Qg + (size_t)bw * L * C + h * 32;
    const float* kb = Kg + (size_t)bw * L * C + h * 32;
    const float* vb = Vg + (size_t)bw * L * C + h * 32;
    const int b = bw / NW;
    const float* pb = Pg + (size_t)(b * H + h) * L * L;
    float* xb = Xout + (size_t)bw * L * C + h * 32;
    float* ab = Aout + ((size_t)bw * H + h) * L * L;

    const float scale = __expf(fminf(LSg[h], LOGIT_MAX_F));

    // ---- Stage: Q,K split hi/lo bf16 rows [64][40]; V transposed bf16 [32][72] ----
    {
        const int r8 = t >> 2;           // row 0..63
        const int c8 = (t & 3) * 8;      // col base 0,8,16,24
        const float4 q0 = *(const float4*)(qb + r8 * C + c8);
        const float4 q1 = *(const float4*)(qb + r8 * C + c8 + 4);
        const float4 k0 = *(const float4*)(kb + r8 * C + c8);
        const float4 k1 = *(const float4*)(kb + r8 * C + c8 + 4);
        const float qa[8] = {q0.x,q0.y,q0.z,q0.w,q1.x,q1.y,q1.z,q1.w};
        const float ka[8] = {k0.x,k0.y,k0.z,k0.w,k1.x,k1.y,k1.z,k1.w};
        bf16x8 qh, ql, kh, kl;
        #pragma unroll
        for (int i = 0; i < 8; ++i) {
            const short qhi = f2bf(qa[i]);
            qh[i] = qhi; ql[i] = f2bf(qa[i] - bf2f(qhi));
            const short khi = f2bf(ka[i]);
            kh[i] = khi; kl[i] = f2bf(ka[i] - bf2f(khi));
        }
        *(bf16x8*)(smem + QHI_OFF + r8 * 40 + c8) = qh;
        *(bf16x8*)(smem + QLO_OFF + r8 * 40 + c8) = ql;
        *(bf16x8*)(smem + KHI_OFF + r8 * 40 + c8) = kh;
        *(bf16x8*)(smem + KLO_OFF + r8 * 40 + c8) = kl;

        const int kk = t & 63;           // seq pos
        const int db = (t >> 6) * 8;     // d base 0,8,16,24
        const float4 v0 = *(const float4*)(vb + kk * C + db);
        const float4 v1 = *(const float4*)(vb + kk * C + db + 4);
        const float va[8] = {v0.x,v0.y,v0.z,v0.w,v1.x,v1.y,v1.z,v1.w};
        #pragma unroll
        for (int i = 0; i < 8; ++i)
            smem[VT_OFF + (db + i) * 72 + kk] = f2bf(va[i]);
    }
    __syncthreads();

    // ---- QK^T: wave w owns q-rows 16w..16w+15; S block 16x64 = 4 tiles ----
    f32x4 acc0 = {0,0,0,0}, acc1 = {0,0,0,0}, acc2 = {0,0,0,0}, acc3 = {0,0,0,0};
    {
        const bf16x8 aqh = *(const bf16x8*)(smem + QHI_OFF + (16*wave + l15)*40 + quad*8);
        const bf16x8 aql = *(const bf16x8*)(smem + QLO_OFF + (16*wave + l15)*40 + quad*8);
        #pragma unroll
        for (int t4 = 0; t4 < 4; ++t4) {
            const bf16x8 bkh = *(const bf16x8*)(smem + KHI_OFF + (16*t4 + l15)*40 + quad*8);
            const bf16x8 bkl = *(const bf16x8*)(smem + KLO_OFF + (16*t4 + l15)*40 + quad*8);
            f32x4 a = (t4==0)?acc0:(t4==1)?acc1:(t4==2)?acc2:acc3;
            a = __builtin_amdgcn_mfma_f32_16x16x32_bf16(aqh, bkh, a, 0, 0, 0);
            a = __builtin_amdgcn_mfma_f32_16x16x32_bf16(aqh, bkl, a, 0, 0, 0);
            a = __builtin_amdgcn_mfma_f32_16x16x32_bf16(aql, bkh, a, 0, 0, 0);
            if (t4==0) acc0 = a; else if (t4==1) acc1 = a; else if (t4==2) acc2 = a; else acc3 = a;
        }
    }

    // ---- logits = acc*scale + pos;  C/D layout: row=quad*4+r (+16w), col=l15+16*t4 ----
    float lg[4][4];
    #pragma unroll
    for (int r = 0; r < 4; ++r) {
        const int row = 16*wave + quad*4 + r;
        const int cb  = row * L + l15;
        lg[0][r] = fmaf(acc0[r], scale, pb[cb + 0]);
        lg[1][r] = fmaf(acc1[r], scale, pb[cb + 16]);
        lg[2][r] = fmaf(acc2[r], scale, pb[cb + 32]);
        lg[3][r] = fmaf(acc3[r], scale, pb[cb + 48]);
    }

    // ---- softmax per row: reduce over 4 tiles (regs) x 16 lanes (xor shuffles) ----
    float p[4][4];
    #pragma unroll
    for (int r = 0; r < 4; ++r) {
        float m = fmaxf(fmaxf(lg[0][r], lg[1][r]), fmaxf(lg[2][r], lg[3][r]));
        #pragma unroll
        for (int off = 8; off > 0; off >>= 1) m = fmaxf(m, __shfl_xor(m, off));
        const float e0 = __expf(lg[0][r] - m);
        const float e1 = __expf(lg[1][r] - m);
        const float e2 = __expf(lg[2][r] - m);
        const float e3 = __expf(lg[3][r] - m);
        float s = (e0 + e1) + (e2 + e3);
        #pragma unroll
        for (int off = 8; off > 0; off >>= 1) s += __shfl_xor(s, off);
        const float inv = 1.0f / s;
        p[0][r] = e0 * inv; p[1][r] = e1 * inv; p[2][r] = e2 * inv; p[3][r] = e3 * inv;
    }

    // barrier before P (bf16) writes: P aliases the Q hi/lo region
    __syncthreads();

    #pragma unroll
    for (int r = 0; r < 4; ++r) {
        const int row = 16*wave + quad*4 + r;
        #pragma unroll
        for (int t4 = 0; t4 < 4; ++t4) {
            const int col = 16*t4 + l15;
            ab[row * L + col] = p[t4][r];                 // attn out, fp32 exact
            smem[P_OFF + row * 72 + col] = f2bf(p[t4][r]); // P for PV, bf16
        }
    }

    // ---- PV: O[16x32] per wave = P[16x64] x V[64x32], two K-halves x two n-tiles ----
    f32x4 o0 = {0,0,0,0}, o1 = {0,0,0,0};
    #pragma unroll
    for (int hh = 0; hh < 2; ++hh) {
        const bf16x8 ap = *(const bf16x8*)(smem + P_OFF + (16*wave + l15)*72 + hh*32 + quad*8);
        const bf16x8 bv0 = *(const bf16x8*)(smem + VT_OFF + l15*72        + hh*32 + quad*8);
        const bf16x8 bv1 = *(const bf16x8*)(smem + VT_OFF + (l15+16)*72   + hh*32 + quad*8);
        o0 = __builtin_amdgcn_mfma_f32_16x16x32_bf16(ap, bv0, o0, 0, 0, 0);
        o1 = __builtin_amdgcn_mfma_f32_16x16x32_bf16(ap, bv1, o1, 0, 0, 0);
    }

    #pragma unroll
    for (int r = 0; r < 4; ++r) {
        const int row = 16*wave + quad*4 + r;
        xb[row * C + l15]      = o0[r];
        xb[row * C + 16 + l15] = o1[r];
    }
}

extern "C" void kernel_launch(void* const* d_in, const int* in_sizes, int n_in,
                              void* d_out, int out_size, void* d_ws, size_t ws_size,
                              hipStream_t stream) {
    const float* q   = (const float*)d_in[0];
    const float* k   = (const float*)d_in[1];
    const float* v   = (const float*)d_in[2];
    const float* pos = (const float*)d_in[3];
    const float* ls  = (const float*)d_in[4];
    float* out = (float*)d_out;

    constexpr int B = 16, NW = 100, L = 64, C = 256, H = 8;
    float* x_out = out;
    float* a_out = out + (size_t)B * NW * L * C;

    const int blocks = B * NW * H;   // 12800
    tat_attn_kernel<<<blocks, 256, 0, stream>>>(q, k, v, pos, ls, x_out, a_out);
}